// Round 1
// baseline (251.403 us; speedup 1.0000x reference)
//
#include <hip/hip_runtime.h>
#include <hip/hip_bf16.h>

// Problem constants (from reference)
#define BB 4
#define CC 64
#define NXX 432
#define NYY 496
#define GG (NXX * NYY)          // 214272 cells per batch
#define PP 80000                // total pillars (B * P_PER)

typedef float v4f __attribute__((ext_vector_type(4)));

// Reference reduces to a dense BEV scatter: prob_buf is zeros (kept bug) so
// p == 0 -> out = spatial. Output [B,C,NY,NX] = pillar_features scattered.

// Workspace layout: [0, B*G) int cell->pillar map, then 64 floats of zeros
// (a "zero pillar row" that empty cells gather from -- removes all per-element
// cndmask selects in the hot kernel).
#define ZROW_INT_OFF (BB * GG)

// Kernel 1: init cell->pillar map to -1, and zero the zero-row.
__global__ void k_init_map(int* __restrict__ map) {
    int i = blockIdx.x * blockDim.x + threadIdx.x;   // one int4 per thread
    const int n4 = (BB * GG) / 4;                    // 214272
    if (i < n4) {
        ((int4*)map)[i] = make_int4(-1, -1, -1, -1);
    }
    if (i < 16) {                                    // 64 floats = 16 int4
        ((int4*)(map + ZROW_INT_OFF))[i] = make_int4(0, 0, 0, 0);
    }
}

// Kernel 2: scatter pillar ids into the map (coords unique per batch).
__global__ void k_scatter_ids(const int* __restrict__ coords, int* __restrict__ map) {
    int i = blockIdx.x * blockDim.x + threadIdx.x;
    if (i < PP) {
        int4 cd = ((const int4*)coords)[i];          // (b, z, y, x), z == 0
        int g = cd.x * GG + cd.y + cd.z * NXX + cd.w;
        map[g] = i;
    }
}

// Kernel 3: gather. Thread = 4 consecutive cells x 8 channels (grid.y slice).
// vs previous version: 8 slices of 8 channels (was 4 of 16) halves per-thread
// register state (8 v4f data regs instead of 16) -> target <=64 VGPR so 8
// waves/SIMD are resident (was ~4-5), doubling the number of in-flight LLC
// gathers per SIMD. Empty cells gather from the L1-hot zero row instead of
// being fixed up with cndmask selects.
__global__ void __launch_bounds__(256, 8) k_gather(const float* __restrict__ pf,
                                                   const int* __restrict__ map,
                                                   float* __restrict__ out) {
    int t = blockIdx.x * blockDim.x + threadIdx.x;   // cell-quad id
    const int nGroups = (BB * GG) / 4;               // 214272 = 837*256 exactly
    if (t >= nGroups) return;

    int cellBase = t * 4;
    int b = cellBase / GG;                           // G%4==0: quad never crosses batch
    int cellInB = cellBase - b * GG;

    int4 pids = ((const int4*)map)[t];
    const v4f* pf4 = (const v4f*)pf;                 // pf rows: 64 floats = 16 vec4
    const v4f* z4  = (const v4f*)(map + ZROW_INT_OFF);

    // Per-pillar base pointer: valid -> its pf row, invalid -> zero row.
    const v4f* p0 = (pids.x >= 0) ? (pf4 + pids.x * 16) : z4;
    const v4f* p1 = (pids.y >= 0) ? (pf4 + pids.y * 16) : z4;
    const v4f* p2 = (pids.z >= 0) ? (pf4 + pids.z * 16) : z4;
    const v4f* p3 = (pids.w >= 0) ? (pf4 + pids.w * 16) : z4;

    int q2 = blockIdx.y * 2;                         // this slice: quads q2, q2+1
    float* outBase = out + (size_t)(b * CC) * GG + cellInB;

    // Issue all 8 loads up front (independent, unconditional -> pipelined).
    v4f r[2][4];
    #pragma unroll
    for (int j = 0; j < 2; ++j) {
        r[j][0] = p0[q2 + j];
        r[j][1] = p1[q2 + j];
        r[j][2] = p2[q2 + j];
        r[j][3] = p3[q2 + j];
    }

    #pragma unroll
    for (int j = 0; j < 2; ++j) {
        int c0 = (q2 + j) * 4;                       // first of 4 channels
        v4f w0 = (v4f){r[j][0].x, r[j][1].x, r[j][2].x, r[j][3].x};
        v4f w1 = (v4f){r[j][0].y, r[j][1].y, r[j][2].y, r[j][3].y};
        v4f w2 = (v4f){r[j][0].z, r[j][1].z, r[j][2].z, r[j][3].z};
        v4f w3 = (v4f){r[j][0].w, r[j][1].w, r[j][2].w, r[j][3].w};

        __builtin_nontemporal_store(w0, (v4f*)(outBase + (size_t)(c0 + 0) * GG));
        __builtin_nontemporal_store(w1, (v4f*)(outBase + (size_t)(c0 + 1) * GG));
        __builtin_nontemporal_store(w2, (v4f*)(outBase + (size_t)(c0 + 2) * GG));
        __builtin_nontemporal_store(w3, (v4f*)(outBase + (size_t)(c0 + 3) * GG));
    }
}

extern "C" void kernel_launch(void* const* d_in, const int* in_sizes, int n_in,
                              void* d_out, int out_size, void* d_ws, size_t ws_size,
                              hipStream_t stream) {
    const float* pf     = (const float*)d_in[0];     // [80000, 64] f32
    const int*   coords = (const int*)d_in[7];       // [80000, 4] i32 (b,z,y,x)
    float*       out    = (float*)d_out;             // [B, C, NY, NX] f32
    int*         map    = (int*)d_ws;                // [B*G] i32 + 64-float zero row

    const int n4 = (BB * GG) / 4;                    // 214272
    k_init_map<<<dim3((n4 + 255) / 256), dim3(256), 0, stream>>>(map);
    k_scatter_ids<<<dim3((PP + 255) / 256), dim3(256), 0, stream>>>(coords, map);

    const int nGroups = (BB * GG) / 4;               // 214272 = 837 * 256 exactly
    dim3 grid((nGroups + 255) / 256, 8);             // 837 x 8 blocks, 8 ch each
    k_gather<<<grid, dim3(256), 0, stream>>>(pf, map, out);
}